// Round 10
// baseline (218.563 us; speedup 1.0000x reference)
//
#include <hip/hip_runtime.h>
#include <hip/hip_bf16.h>

// GAT layer, B=4, N=4096, F_in=128, F_out=64.
// out_i = sum_j adj_ij * exp(leaky(s2_i+s1_j)) * Wh_j / sum_j adj_ij*exp(..)
// (softmax normalizer cancels; eps*Z term is 2e-9 relative -> dropped;
//  scores O(8) so bare exp2 is safe; s1/s2 pre-scaled by log2 e.)
//
// R10 = R9 with ONE change: k_main __launch_bounds__(256,3) -> 3 blocks/CU
// (12 waves, 3 barrier-groups). R9's per-step arithmetic shows VALU/LDS/L1
// all far under budget; the residual ~25% over the adj-stream floor is
// barrier-lockstep starvation at 2 blocks/CU. VGPR audit ~152 < 170 cap.

typedef __attribute__((ext_vector_type(8))) short bf16x8;
typedef __attribute__((ext_vector_type(4))) float f32x4;
typedef __attribute__((ext_vector_type(4))) unsigned int u32x4;

#define LOG2E 1.4426950408889634f

__device__ __forceinline__ unsigned int pk2(float lo, float hi) {
  float2 f2; f2.x = lo; f2.y = hi;
  union { __hip_bfloat162 b; unsigned int u; } c;
  c.b = __float22bfloat162_rn(f2);
  return c.u;
}
__device__ __forceinline__ bf16x8 u2b(u32x4 v) {
  union { u32x4 u; bf16x8 b; } c; c.u = v; return c.b;
}
__device__ __forceinline__ float vexp2_(float x) {
  float r; asm("v_exp_f32 %0, %1" : "=v"(r) : "v"(x)); return r;
}

// ---------------- K1: Wh = h @ W (f32); wt bf16 in fragment order;
//                  s1 = Wh a1 * log2e, s2 = Wh a2 * log2e
__global__ __launch_bounds__(256) void k_wh(
    const float* __restrict__ h, const float* __restrict__ W, const float* __restrict__ a,
    unsigned short* __restrict__ wt, float* __restrict__ s1, float* __restrict__ s2) {
  __shared__ float hs[32][130];
  __shared__ float Ws[128 * 64];
  const int t = threadIdx.x;
  const int b = blockIdx.x >> 7;
  const int row0 = (blockIdx.x & 127) << 5;

  // stage W (32KB) into LDS, once
  #pragma unroll
  for (int it = 0; it < 8; ++it) {
    const int fidx = it * 256 + t;
    ((float4*)Ws)[fidx] = ((const float4*)W)[fidx];
  }
  // stage h tile: 32 rows x 128 f32
  #pragma unroll
  for (int it = 0; it < 4; ++it) {
    int flat = it * 256 + t;
    int r = flat >> 5, q = flat & 31;
    const float4 v = *(const float4*)(h + ((size_t)(b * 4096 + row0 + r)) * 128 + 4 * q);
    hs[r][4*q+0] = v.x; hs[r][4*q+1] = v.y; hs[r][4*q+2] = v.z; hs[r][4*q+3] = v.w;
  }
  __syncthreads();

  const int rg = t >> 4, cg = t & 15;
  float acc[2][4] = {};
  for (int k = 0; k < 128; ++k) {
    float4 wv = ((const float4*)Ws)[k * 16 + cg];   // LDS b128, 2-way max
    #pragma unroll
    for (int i = 0; i < 2; ++i) {
      float hv = hs[2*rg + i][k];
      acc[i][0] = fmaf(hv, wv.x, acc[i][0]);
      acc[i][1] = fmaf(hv, wv.y, acc[i][1]);
      acc[i][2] = fmaf(hv, wv.z, acc[i][2]);
      acc[i][3] = fmaf(hv, wv.w, acc[i][3]);
    }
  }
  __syncthreads();

  float (*WhF)[68] = (float(*)[68])hs;
  #pragma unroll
  for (int i = 0; i < 2; ++i)
    #pragma unroll
    for (int j = 0; j < 4; ++j)
      WhF[2*rg + i][4*cg + j] = acc[i][j];
  __syncthreads();

  if (t < 32) {
    float x1 = 0.f, x2 = 0.f;
    #pragma unroll 8
    for (int c = 0; c < 64; ++c) {
      float v = WhF[t][c];
      x1 = fmaf(v, a[c], x1);
      x2 = fmaf(v, a[64 + c], x2);
    }
    s1[b * 4096 + row0 + t] = x1 * LOG2E;
    s2[b * 4096 + row0 + t] = x2 * LOG2E;
  }

  // fragment-order store: this tile covers kk32 = row0>>5 exactly.
  const int col = t >> 2, sub = t & 3;   // sub = (k%32)/8
  unsigned int uh[4];
  #pragma unroll
  for (int r = 0; r < 4; ++r)
    uh[r] = pk2(WhF[8*sub + 2*r][col], WhF[8*sub + 2*r + 1][col]);
  const int S = (b * 128 + (row0 >> 5)) * 4 + (col >> 4);
  unsigned short* dst = wt + ((size_t)S << 9) + sub * 128 + (col & 15) * 8;
  *(uint4*)dst = make_uint4(uh[0], uh[1], uh[2], uh[3]);
}

// ---------------- K3: out = P @ Wh, K-step 256.
// 512 blocks x 256 thr (4 waves, 3 blocks/CU). Wave w owns adj rows 8w..8w+7
// (1KB-contiguous loads) and output cols 16w..16w+16 (B private, contiguous
// 1KB fragment loads). P: registers -> swizzled LDS -> A-frags.
__global__ __launch_bounds__(256, 3) void k_main(
    const float* __restrict__ adj, const unsigned short* __restrict__ wt,
    const float* __restrict__ s1, const float* __restrict__ s2,
    float* __restrict__ out) {
  __shared__ unsigned short Pws[2][8192];   // 2 x (32 rows x 512B, XOR-swizzled)
  __shared__ float Ss[32];

  const int t = threadIdx.x;
  const int blk = blockIdx.x;
  const int xcd = blk & 7;                   // default round-robin XCD id
  const int b = xcd >> 1;                    // one batch per XCD pair: wt L2-resident
  const int tile = (blk >> 3) + ((xcd & 1) << 6);   // 0..127 bijective per b
  const int row0 = tile << 5;
  const int l = t & 63, w = t >> 6;
  const int lr = l & 15, g = l >> 4;

  const float* adjW = adj + ((size_t)(b * 4096 + row0 + 8 * w)) * 4096 + 4 * l;
  const float* s1W  = s1 + b * 4096 + 4 * l;
  // fragment-order B base for this wave: segment (b*128 + kk32)*4 + w
  const unsigned short* wtW = wt + (((size_t)(b * 128) * 4 + w) << 9) + 8 * l;

  float s2r[8];
  #pragma unroll
  for (int r = 0; r < 8; ++r) s2r[r] = s2[b * 4096 + row0 + 8 * w + r];

  float sar[8] = {0.f,0.f,0.f,0.f,0.f,0.f,0.f,0.f};
  f32x4 acc0 = {0.f,0.f,0.f,0.f}, acc1 = {0.f,0.f,0.f,0.f};

  f32x4 aX[8], aY[8], sX, sY;
  u32x4 bv[8];

#define LOADADJ(av, sv, ks) do {                                              \
    const int ko = ((ks) & 15) << 8;                                          \
    _Pragma("unroll")                                                         \
    for (int r = 0; r < 8; ++r)                                               \
      av[r] = *(const f32x4*)(adjW + (size_t)r * 4096 + ko);                  \
    sv = *(const f32x4*)(s1W + ko);                                           \
  } while (0)

  // 8 contiguous 1KB loads: kk32 = ksm*8 + kk, stride 4 segments (2048 shorts)
#define LOADB(ks) do {                                                        \
    const int ksm = (ks) & 15;                                                \
    const unsigned short* bp = wtW + ((size_t)(ksm * 8) << 11);               \
    _Pragma("unroll")                                                         \
    for (int kk = 0; kk < 8; ++kk)                                            \
      bv[kk] = *(const u32x4*)(bp + (kk << 11));                              \
  } while (0)

  // lane l holds rows 8w..8w+7, cols [4l,4l+4). Write 8B to swizzled P row:
  // element col c of row r8 lives at short-offset c ^ ((r8&7)<<3).
#define PBUILD(av, sv, buf) do {                                              \
    unsigned short* Pd = &Pws[buf][0];                                        \
    _Pragma("unroll")                                                         \
    for (int r = 0; r < 8; ++r) {                                             \
      float e0 = s2r[r] + sv[0], e1 = s2r[r] + sv[1];                         \
      float e2 = s2r[r] + sv[2], e3 = s2r[r] + sv[3];                         \
      e0 = fmaxf(e0, 0.2f * e0); e1 = fmaxf(e1, 0.2f * e1);                   \
      e2 = fmaxf(e2, 0.2f * e2); e3 = fmaxf(e3, 0.2f * e3);                   \
      float p0 = vexp2_(e0), p1 = vexp2_(e1);                                 \
      float p2 = vexp2_(e2), p3 = vexp2_(e3);                                 \
      float w0 = av[r][0] * p0, w1 = av[r][1] * p1;                           \
      float w2 = av[r][2] * p2, w3 = av[r][3] * p3;                           \
      sar[r] += (w0 + w1) + (w2 + w3);                                        \
      uint2 pk; pk.x = pk2(w0, w1); pk.y = pk2(w2, w3);                       \
      *(uint2*)(Pd + (8 * w + r) * 256 + ((4 * l) ^ (r << 3))) = pk;          \
    }                                                                         \
  } while (0)

#define SYNC() do {                                                           \
    asm volatile("s_waitcnt lgkmcnt(0)" ::: "memory");                        \
    __builtin_amdgcn_sched_barrier(0);                                        \
    __builtin_amdgcn_s_barrier();                                             \
    __builtin_amdgcn_sched_barrier(0);                                        \
  } while (0)

#define MFMAP(buf) do {                                                       \
    const unsigned short* Pr = &Pws[buf][0];                                  \
    _Pragma("unroll")                                                         \
    for (int kk = 0; kk < 8; ++kk) {                                          \
      const int koff = (8 * g + 32 * kk) ^ ((lr & 7) << 3);                   \
      bf16x8 a0 = *(const bf16x8*)(Pr + lr * 256 + koff);                     \
      bf16x8 a1 = *(const bf16x8*)(Pr + (16 + lr) * 256 + koff);              \
      acc0 = __builtin_amdgcn_mfma_f32_16x16x32_bf16(a0, u2b(bv[kk]), acc0, 0, 0, 0); \
      acc1 = __builtin_amdgcn_mfma_f32_16x16x32_bf16(a1, u2b(bv[kk]), acc1, 0, 0, 0); \
    }                                                                         \
  } while (0)

  LOADADJ(aX, sX, 0);
  LOADADJ(aY, sY, 1);
  LOADB(0);

  for (int it = 0; it < 8; ++it) {
    PBUILD(aX, sX, 0);
    LOADADJ(aX, sX, 2 * it + 2);   // depth-2 HBM prefetch (wraps harmlessly)
    SYNC();                        // lgkm only: HBM prefetch stays in flight
    MFMAP(0);
    LOADB(2 * it + 1);             // B(s+1): in flight across next P-build

    PBUILD(aY, sY, 1);
    LOADADJ(aY, sY, 2 * it + 3);
    SYNC();
    MFMAP(1);
    LOADB(2 * it + 2);
  }

  // S row sums: full-wave butterfly per row, lane 0 publishes
  #pragma unroll
  for (int r = 0; r < 8; ++r) {
    float v = sar[r];
    #pragma unroll
    for (int m = 1; m < 64; m <<= 1) v += __shfl_xor(v, m);
    sar[r] = v;
  }
  if (l == 0) {
    #pragma unroll
    for (int r = 0; r < 8; ++r) Ss[8 * w + r] = sar[r];
  }
  __syncthreads();

  // epilogue: out = acc / S ; C layout col=lr, row=4g+reg (+16 for acc1)
  #pragma unroll
  for (int reg = 0; reg < 4; ++reg) {
    const int r0 = 4 * g + reg, r1 = 16 + 4 * g + reg;
    const float i0 = 1.0f / Ss[r0], i1 = 1.0f / Ss[r1];
    const size_t ob = ((size_t)(b * 4096 + row0 + r0)) * 64 + 16 * w + lr;
    out[ob] = acc0[reg] * i0;
    out[ob + (size_t)16 * 64] = acc1[reg] * i1;
  }
}

extern "C" void kernel_launch(void* const* d_in, const int* in_sizes, int n_in,
                              void* d_out, int out_size, void* d_ws, size_t ws_size,
                              hipStream_t stream) {
  const float* h   = (const float*)d_in[0];
  const float* adj = (const float*)d_in[1];
  const float* W   = (const float*)d_in[2];
  const float* a   = (const float*)d_in[3];
  float* out = (float*)d_out;

  // ws layout: wt (2MB bf16, fragment order) | s1 (64KB) | s2 (64KB)
  unsigned short* wt = (unsigned short*)d_ws;
  float* s1 = (float*)(wt + (size_t)4 * 64 * 4096);
  float* s2 = s1 + 16384;

  k_wh  <<<512, 256, 0, stream>>>(h, W, a, wt, s1, s2);
  k_main<<<512, 256, 0, stream>>>(adj, wt, s1, s2, out);
}

// Round 11
// 66.821 us; speedup vs baseline: 3.2709x; 3.2709x over previous
//
#include <hip/hip_runtime.h>
#include <hip/hip_bf16.h>

// GAT layer, B=4, N=4096, F_in=128, F_out=64.
// out_i = sum_j adj_ij * exp(leaky(s2_i+s1_j)) * Wh_j / sum_j adj_ij*exp(..)
// (softmax normalizer cancels; eps*Z term is 2e-9 relative -> dropped;
//  scores O(8) so bare exp2 is safe; s1/s2 pre-scaled by log2 e.)
//
// R11: 4 blocks/CU honestly. 16-row x 64-col tiles, K-step 128, 1024 blocks
// (grid-resident 4/CU), per-thread footprint ~80 VGPR (<=128 granule, capped
// by launch_bounds(256,4) -> no spill), 16 waves/CU = 4 barrier-groups.
// R10's failure: (256,3) is unreachable in the 64/128/256 VGPR granule ->
// compiler spilled 2.6KB/thread (WRITE_SIZE 345MB). Keep R9's validated
// fragment-order B, XOR-swizzled P, plain adj loads, lgkm-only SYNC.

typedef __attribute__((ext_vector_type(8))) short bf16x8;
typedef __attribute__((ext_vector_type(4))) float f32x4;
typedef __attribute__((ext_vector_type(4))) unsigned int u32x4;

#define LOG2E 1.4426950408889634f

__device__ __forceinline__ unsigned int pk2(float lo, float hi) {
  float2 f2; f2.x = lo; f2.y = hi;
  union { __hip_bfloat162 b; unsigned int u; } c;
  c.b = __float22bfloat162_rn(f2);
  return c.u;
}
__device__ __forceinline__ bf16x8 u2b(u32x4 v) {
  union { u32x4 u; bf16x8 b; } c; c.u = v; return c.b;
}
__device__ __forceinline__ float vexp2_(float x) {
  float r; asm("v_exp_f32 %0, %1" : "=v"(r) : "v"(x)); return r;
}

// ---------------- K1: Wh = h @ W (f32); wt bf16 in fragment order
//   segment S = (b*128 + k/32)*4 + col/16 (1KB); lane ((k%32)/8)*16+col%16
//   holds 8 shorts. s1 = Wh a1 * log2e, s2 = Wh a2 * log2e.
__global__ __launch_bounds__(256) void k_wh(
    const float* __restrict__ h, const float* __restrict__ W, const float* __restrict__ a,
    unsigned short* __restrict__ wt, float* __restrict__ s1, float* __restrict__ s2) {
  __shared__ float hs[32][130];
  __shared__ float Ws[128 * 64];
  const int t = threadIdx.x;
  const int b = blockIdx.x >> 7;
  const int row0 = (blockIdx.x & 127) << 5;

  #pragma unroll
  for (int it = 0; it < 8; ++it) {
    const int fidx = it * 256 + t;
    ((float4*)Ws)[fidx] = ((const float4*)W)[fidx];
  }
  #pragma unroll
  for (int it = 0; it < 4; ++it) {
    int flat = it * 256 + t;
    int r = flat >> 5, q = flat & 31;
    const float4 v = *(const float4*)(h + ((size_t)(b * 4096 + row0 + r)) * 128 + 4 * q);
    hs[r][4*q+0] = v.x; hs[r][4*q+1] = v.y; hs[r][4*q+2] = v.z; hs[r][4*q+3] = v.w;
  }
  __syncthreads();

  const int rg = t >> 4, cg = t & 15;
  float acc[2][4] = {};
  for (int k = 0; k < 128; ++k) {
    float4 wv = ((const float4*)Ws)[k * 16 + cg];
    #pragma unroll
    for (int i = 0; i < 2; ++i) {
      float hv = hs[2*rg + i][k];
      acc[i][0] = fmaf(hv, wv.x, acc[i][0]);
      acc[i][1] = fmaf(hv, wv.y, acc[i][1]);
      acc[i][2] = fmaf(hv, wv.z, acc[i][2]);
      acc[i][3] = fmaf(hv, wv.w, acc[i][3]);
    }
  }
  __syncthreads();

  float (*WhF)[68] = (float(*)[68])hs;
  #pragma unroll
  for (int i = 0; i < 2; ++i)
    #pragma unroll
    for (int j = 0; j < 4; ++j)
      WhF[2*rg + i][4*cg + j] = acc[i][j];
  __syncthreads();

  if (t < 32) {
    float x1 = 0.f, x2 = 0.f;
    #pragma unroll 8
    for (int c = 0; c < 64; ++c) {
      float v = WhF[t][c];
      x1 = fmaf(v, a[c], x1);
      x2 = fmaf(v, a[64 + c], x2);
    }
    s1[b * 4096 + row0 + t] = x1 * LOG2E;
    s2[b * 4096 + row0 + t] = x2 * LOG2E;
  }

  const int col = t >> 2, sub = t & 3;
  unsigned int uh[4];
  #pragma unroll
  for (int r = 0; r < 4; ++r)
    uh[r] = pk2(WhF[8*sub + 2*r][col], WhF[8*sub + 2*r + 1][col]);
  const int S = (b * 128 + (row0 >> 5)) * 4 + (col >> 4);
  unsigned short* dst = wt + ((size_t)S << 9) + sub * 128 + (col & 15) * 8;
  *(uint4*)dst = make_uint4(uh[0], uh[1], uh[2], uh[3]);
}

// ---------------- K3: out = P @ Wh. 1024 blocks x 256 thr, 4 blocks/CU.
// Block tile: 16 rows x 64 cols, K-step 128 (32 steps, 1 barrier each).
// Wave w: P rows 4w..4w+3 (lane: rows 4w+2i+(l>>5), cols 4(l&31)..+4),
// MFMA cols 16w..16w+16 (contiguous fragment-order B, bv[4]).
__global__ __launch_bounds__(256, 4) void k_main(
    const float* __restrict__ adj, const unsigned short* __restrict__ wt,
    const float* __restrict__ s1, const float* __restrict__ s2,
    float* __restrict__ out) {
  __shared__ unsigned short Pws[2][2048];   // [buf][16 rows][128 shorts], swizzled
  __shared__ float Ss[16];

  const int t = threadIdx.x;
  const int blk = blockIdx.x;
  const int xcd = blk & 7;                    // default round-robin XCD id
  const int b = xcd >> 1;                     // one batch per XCD pair
  const int tile = (blk >> 3) + ((xcd & 1) << 7);   // 0..255 bijective per b
  const int row0 = tile << 4;
  const int l = t & 63, w = t >> 6;
  const int lr = l & 15, g = l >> 4;
  const int lh = l >> 5, lc = l & 31;         // row-pair half / col lane

  const float* adjW = adj + ((size_t)(b * 4096 + row0 + 4 * w + lh)) * 4096 + 4 * lc;
  const float* s1W  = s1 + b * 4096 + 4 * lc;
  // fragment-order B base for wave w: segment (b*128 + k32)*4 + w
  const unsigned short* wtW = wt + (((size_t)b * 512 + w) << 9) + 8 * l;

  float s2v[2];
  #pragma unroll
  for (int i = 0; i < 2; ++i)
    s2v[i] = s2[b * 4096 + row0 + 4 * w + 2 * i + lh];

  float sar[2] = {0.f, 0.f};
  f32x4 acc = {0.f, 0.f, 0.f, 0.f};

  f32x4 aX[2], aY[2], sX, sY;
  u32x4 bv[4];

#define LOADADJ(av, sv, ks) do {                                              \
    const int ko = ((ks) & 31) << 7;                                          \
    av[0] = *(const f32x4*)(adjW + ko);                                       \
    av[1] = *(const f32x4*)(adjW + 8192 + ko);                                \
    sv = *(const f32x4*)(s1W + ko);                                           \
  } while (0)

  // 4 contiguous 1KB fragment loads for k32 = ksm*4 + kk
#define LOADB(ks) do {                                                        \
    const int ksm = (ks) & 31;                                                \
    _Pragma("unroll")                                                         \
    for (int kk = 0; kk < 4; ++kk)                                            \
      bv[kk] = *(const u32x4*)(wtW + (size_t)(ksm * 4 + kk) * 2048);          \
  } while (0)

  // lane holds rows 4w+2i+lh (i=0,1), cols [4lc,4lc+4). Swizzled P write:
  // col c of local row r lives at short-offset c ^ ((r&7)<<3).
#define PBUILD(av, sv, buf) do {                                              \
    unsigned short* Pd = &Pws[buf][0];                                        \
    _Pragma("unroll")                                                         \
    for (int i = 0; i < 2; ++i) {                                             \
      const int rl = 4 * w + 2 * i + lh;                                      \
      float e0 = s2v[i] + sv[0], e1 = s2v[i] + sv[1];                         \
      float e2 = s2v[i] + sv[2], e3 = s2v[i] + sv[3];                         \
      e0 = fmaxf(e0, 0.2f * e0); e1 = fmaxf(e1, 0.2f * e1);                   \
      e2 = fmaxf(e2, 0.2f * e2); e3 = fmaxf(e3, 0.2f * e3);                   \
      float p0 = vexp2_(e0), p1 = vexp2_(e1);                                 \
      float p2 = vexp2_(e2), p3 = vexp2_(e3);                                 \
      float w0 = av[i][0] * p0, w1 = av[i][1] * p1;                           \
      float w2 = av[i][2] * p2, w3 = av[i][3] * p3;                           \
      sar[i] += (w0 + w1) + (w2 + w3);                                        \
      uint2 pk; pk.x = pk2(w0, w1); pk.y = pk2(w2, w3);                       \
      *(uint2*)(Pd + rl * 128 + ((4 * lc) ^ ((rl & 7) << 3))) = pk;           \
    }                                                                         \
  } while (0)

#define SYNC() do {                                                           \
    asm volatile("s_waitcnt lgkmcnt(0)" ::: "memory");                        \
    __builtin_amdgcn_sched_barrier(0);                                        \
    __builtin_amdgcn_s_barrier();                                             \
    __builtin_amdgcn_sched_barrier(0);                                        \
  } while (0)

#define MFMAP(buf) do {                                                       \
    const unsigned short* Pr = &Pws[buf][0];                                  \
    _Pragma("unroll")                                                         \
    for (int kk = 0; kk < 4; ++kk) {                                          \
      const int koff = (8 * g + 32 * kk) ^ ((lr & 7) << 3);                   \
      bf16x8 a0 = *(const bf16x8*)(Pr + lr * 128 + koff);                     \
      acc = __builtin_amdgcn_mfma_f32_16x16x32_bf16(a0, u2b(bv[kk]), acc, 0, 0, 0); \
    }                                                                         \
  } while (0)

  LOADADJ(aX, sX, 0);
  LOADADJ(aY, sY, 1);
  LOADB(0);

  for (int it = 0; it < 16; ++it) {
    PBUILD(aX, sX, 0);
    LOADADJ(aX, sX, 2 * it + 2);   // depth-2 HBM prefetch (wraps harmlessly)
    SYNC();                        // lgkm only: HBM prefetch stays in flight
    MFMAP(0);
    LOADB(2 * it + 1);             // L2 B for next step, in flight over PBUILD

    PBUILD(aY, sY, 1);
    LOADADJ(aY, sY, 2 * it + 3);
    SYNC();
    MFMAP(1);
    LOADB(2 * it + 2);
  }

  // row sums: butterfly within each 32-lane half; lanes lc==0 publish
  #pragma unroll
  for (int i = 0; i < 2; ++i) {
    float v = sar[i];
    #pragma unroll
    for (int m = 1; m < 32; m <<= 1) v += __shfl_xor(v, m);
    if (lc == 0) Ss[4 * w + 2 * i + lh] = v;
  }
  __syncthreads();

  // epilogue: C layout col=lr, row=4g+reg; out col = 16w + lr
  #pragma unroll
  for (int reg = 0; reg < 4; ++reg) {
    const int r = 4 * g + reg;
    const float inv = 1.0f / Ss[r];
    out[((size_t)(b * 4096 + row0 + r)) * 64 + 16 * w + lr] = acc[reg] * inv;
  }
}

extern "C" void kernel_launch(void* const* d_in, const int* in_sizes, int n_in,
                              void* d_out, int out_size, void* d_ws, size_t ws_size,
                              hipStream_t stream) {
  const float* h   = (const float*)d_in[0];
  const float* adj = (const float*)d_in[1];
  const float* W   = (const float*)d_in[2];
  const float* a   = (const float*)d_in[3];
  float* out = (float*)d_out;

  // ws layout: wt (2MB bf16, fragment order) | s1 (64KB) | s2 (64KB)
  unsigned short* wt = (unsigned short*)d_ws;
  float* s1 = (float*)(wt + (size_t)4 * 64 * 4096);
  float* s2 = s1 + 16384;

  k_wh  <<<512, 256, 0, stream>>>(h, W, a, wt, s1, s2);
  k_main<<<1024, 256, 0, stream>>>(adj, wt, s1, s2, out);
}